// Round 11
// baseline (111.122 us; speedup 1.0000x reference)
//
#include <hip/hip_runtime.h>
#include <hip/hip_fp16.h>

// W8X8Linear: per-row int8 quant (x and w), int8 GEMM via MFMA, dequant+bias.
// M=B*S=32768, N=1024, K=1024 (derived from in_sizes at launch).
//
// Exact-replication notes:
//  - jnp.round == round-half-even == rintf (v_rndne_f32)
//  - scale 127.0f/max (fp32 div) then fp32 mul, like the reference
//  - int32 accumulation == reference's fp32 einsum (|acc| < 2^24, exact)
//  - dequant: * (1/16129), fp16 RN cast, fp32 * (xmax*wmax) + bias
//
// R1: dbuf+XCD swizzle: ~92us GEMM. R2/R7/R8: schedule variants: NULL.
// R3: no-LDS reg GEMM on ROW-MAJOR layout: 158us (frag loads = 16 scattered
//     64B lines). R4: coarse 256^2: 117us. R5: spill: 360us.
// R6: K-BLOCKED quant layout q[kb][row][64]: contiguous staging, 95us.
// R9: thin regs -> 4 waves/SIMD: 89us. Remaining: barrier-locked LDS
//     round-trip keeps LDS pipe + VMEM serialized per tile.
// R10: the K-blocked layout makes fragment loads CONTIGUOUS (1KB/wave-load),
//     which is what R3 lacked -> drop LDS entirely. global->reg->MFMA,
//     ZERO barriers, register double-buffer (two named sets, kt+=2).
//     Per-tile 16KB is L1-resident (frags shared across wave pairs);
//     B + XCD-chunked A slices are L2-resident. 12 waves/CU, free desync.

typedef int i32x4 __attribute__((ext_vector_type(4)));

#define BM 128
#define BN 128
#define KB 64  // K-bytes per tile = quant layout block size

// -------- quantize: one block per row; OUTPUT IS K-BLOCKED q[kb][row][64] ---
__global__ __launch_bounds__(256) void quant_rows_kernel(
    const float* __restrict__ in, signed char* __restrict__ q,
    float* __restrict__ rowmax, int K, int R) {
  const int row = blockIdx.x;
  const int t = threadIdx.x;
  const size_t base = (size_t)row * K;
  float4 v = reinterpret_cast<const float4*>(in + base)[t];
  float a = fmaxf(fmaxf(fabsf(v.x), fabsf(v.y)), fmaxf(fabsf(v.z), fabsf(v.w)));
#pragma unroll
  for (int off = 32; off > 0; off >>= 1) a = fmaxf(a, __shfl_xor(a, off, 64));
  __shared__ float smax[4];
  if ((t & 63) == 0) smax[t >> 6] = a;
  __syncthreads();
  float m = fmaxf(fmaxf(smax[0], smax[1]), fmaxf(smax[2], smax[3]));
  float s = 127.0f / m;  // fp32 divide, same as reference
  char4 qq;
  qq.x = (signed char)(int)rintf(v.x * s);
  qq.y = (signed char)(int)rintf(v.y * s);
  qq.z = (signed char)(int)rintf(v.z * s);
  qq.w = (signed char)(int)rintf(v.w * s);
  // elems k = 4t..4t+3 -> kb = t>>4, within-block byte (t&15)*4
  const int kb = t >> 4;
  signed char* dst = q + (size_t)kb * R * KB + (size_t)row * KB + (t & 15) * 4;
  *reinterpret_cast<char4*>(dst) = qq;
  if (t == 0) rowmax[row] = m;
}

// ------ int8 GEMM, 128x128 tile, 4 waves (2x2), direct global->reg, no LDS --
__global__ __launch_bounds__(256, 3) void w8x8_gemm_kernel(
    const signed char* __restrict__ Aq, const signed char* __restrict__ Bq,
    const float* __restrict__ Amax, const float* __restrict__ Bmax,
    const float* __restrict__ bias, float* __restrict__ out,
    int M, int N, int K, int cpx) {
  const int t = threadIdx.x;
  const int lane = t & 63;
  const int wave = t >> 6;
  const int wrow = wave >> 1, wcol = wave & 1;

  // XCD-chunked swizzle: consecutive blocks on one XCD share bm (bn varies
  // fastest) -> A-tile L2/L1 reuse; per-XCD A slice 4 MB = one L2.
  const int nbn = N / BN;
  const int bid = blockIdx.x;
  const int tile = (bid & 7) * cpx + (bid >> 3);
  const int bm = tile / nbn, bn = tile % nbn;

  // K-blocked layout: tile kt of this block's A-panel is CONTIGUOUS 8 KB at
  // Aq + kt*M*64 + bm*128*64 (rows at 64 B). Fragment load for a wave:
  // lane(fr,fq) -> (rowbase+fr)*64 + fq*16 => 1024 CONTIGUOUS bytes/load.
  const size_t kbA = (size_t)M * KB;
  const size_t kbB = (size_t)N * KB;
  const int fr = lane & 15, fq = lane >> 4;
  const signed char* pa =
      Aq + (size_t)bm * BM * KB + ((wrow * 64 + fr) << 6) + (fq << 4);
  const signed char* pb =
      Bq + (size_t)bn * BN * KB + ((wcol * 64 + fr) << 6) + (fq << 4);

  i32x4 acc[4][4];
#pragma unroll
  for (int m = 0; m < 4; ++m)
#pragma unroll
    for (int n = 0; n < 4; ++n) acc[m][n] = (i32x4){0, 0, 0, 0};

#define LOADF(A_, B_, kt)                                              \
  do {                                                                 \
    const signed char* ga = pa + (size_t)(kt) * kbA;                   \
    const signed char* gb = pb + (size_t)(kt) * kbB;                   \
    A_[0] = *reinterpret_cast<const i32x4*>(ga);                       \
    A_[1] = *reinterpret_cast<const i32x4*>(ga + 1024);                \
    A_[2] = *reinterpret_cast<const i32x4*>(ga + 2048);                \
    A_[3] = *reinterpret_cast<const i32x4*>(ga + 3072);                \
    B_[0] = *reinterpret_cast<const i32x4*>(gb);                       \
    B_[1] = *reinterpret_cast<const i32x4*>(gb + 1024);                \
    B_[2] = *reinterpret_cast<const i32x4*>(gb + 2048);                \
    B_[3] = *reinterpret_cast<const i32x4*>(gb + 3072);                \
  } while (0)

#define MFMA16(A_, B_)                                                   \
  do {                                                                   \
    __builtin_amdgcn_s_setprio(1);                                       \
    _Pragma("unroll") for (int m = 0; m < 4; ++m)                        \
        _Pragma("unroll") for (int n = 0; n < 4; ++n) acc[m][n] =        \
        __builtin_amdgcn_mfma_i32_16x16x64_i8(A_[m], B_[n], acc[m][n],   \
                                              0, 0, 0);                  \
    __builtin_amdgcn_s_setprio(0);                                       \
  } while (0)

  const int NT = K / KB;  // 16 (even)
  // Register double-buffer with NAMED sets (compile-time indices, rule #20).
  i32x4 a0[4], b0[4], a1[4], b1[4];
  LOADF(a0, b0, 0);
  for (int kt = 0; kt < NT; kt += 2) {
    LOADF(a1, b1, kt + 1);     // prefetch odd tile (always valid: NT even)
    MFMA16(a0, b0);            // compute even tile (loads 1 tile of cover)
    if (kt + 2 < NT) LOADF(a0, b0, kt + 2);  // prefetch next even tile
    MFMA16(a1, b1);            // compute odd tile
  }
#undef LOADF
#undef MFMA16

  // Epilogue: C/D layout col = lane&15, row = (lane>>4)*4 + reg.
  const int row0 = bm * BM + wrow * 64;
  const int col0 = bn * BN + wcol * 64;
  const float C = 1.0f / 16129.0f;
  float wmx[4], bs[4];
#pragma unroll
  for (int n = 0; n < 4; ++n) {
    int col = col0 + n * 16 + fr;
    wmx[n] = Bmax[col];
    bs[n] = bias[col];
  }
#pragma unroll
  for (int m = 0; m < 4; ++m) {
#pragma unroll
    for (int r = 0; r < 4; ++r) {
      int row = row0 + m * 16 + fq * 4 + r;
      float xm = Amax[row];
      float* orow = out + (size_t)row * N;
#pragma unroll
      for (int n = 0; n < 4; ++n) {
        float v = (float)acc[m][n][r] * C;
        float h = __half2float(__float2half_rn(v));  // fp16 rounding step
        orow[col0 + n * 16 + fr] = h * (xm * wmx[n]) + bs[n];
      }
    }
  }
}

extern "C" void kernel_launch(void* const* d_in, const int* in_sizes, int n_in,
                              void* d_out, int out_size, void* d_ws, size_t ws_size,
                              hipStream_t stream) {
  const float* x = (const float*)d_in[0];     // [B,S,K] fp32
  const float* w = (const float*)d_in[1];     // [N,K] fp32
  const float* bias = (const float*)d_in[2];  // [N] fp32
  float* out = (float*)d_out;                 // [B,S,N] fp32

  const int N = in_sizes[2];
  const int K = in_sizes[1] / N;   // 1024
  const int M = in_sizes[0] / K;   // 32768

  // workspace layout: x_q | w_q | x_max | w_max  (~34.7 MB total)
  signed char* xq = (signed char*)d_ws;
  signed char* wq = xq + (size_t)M * K;
  float* xmax = (float*)(wq + (size_t)N * K);
  float* wmax = xmax + M;

  quant_rows_kernel<<<M, 256, 0, stream>>>(x, xq, xmax, K, M);
  quant_rows_kernel<<<N, 256, 0, stream>>>(w, wq, wmax, K, N);

  const int nwg = (M / BM) * (N / BN);  // 2048, divisible by 8
  const int cpx = nwg / 8;
  w8x8_gemm_kernel<<<nwg, 256, 0, stream>>>(xq, wq, xmax, wmax, bias, out,
                                            M, N, K, cpx);
}

// Round 12
// 100.260 us; speedup vs baseline: 1.1083x; 1.1083x over previous
//
#include <hip/hip_runtime.h>
#include <hip/hip_fp16.h>

// W8X8Linear: per-row int8 quant (x and w), int8 GEMM via MFMA, dequant+bias.
// M=B*S=32768, N=1024, K=1024 (derived from in_sizes at launch).
//
// Exact-replication notes:
//  - jnp.round == round-half-even == rintf (v_rndne_f32)
//  - scale 127.0f/max (fp32 div) then fp32 mul, like the reference
//  - int32 accumulation == reference's fp32 einsum (|acc| < 2^24, exact)
//  - dequant: * (1/16129), fp16 RN cast, fp32 * (xmax*wmax) + bias
//
// R6: K-BLOCKED quant layout q[kb][row][64] (contiguous staging): 95us.
// R9: thin regs -> 4 waves/SIMD: 89us (best).
// R10: full no-LDS: REGRESSED 111us — VGPR_Count=72 proved the compiler
//      SANK the prefetch loads (nothing pinned them) -> serialized latency.
// R11: hybrid. A: direct global->reg (1KB-contiguous in K-blocked layout),
//      double-buffered NAMED sets, PINNED by the existing asm vmcnt+barrier
//      (memory clobber stops sinking — what R10 lacked). B: LDS-staged
//      (broadcast to all 4 waves, proven swizzle). vmcnt(6) = 2 B-stage +
//      4 A-loads per iter. PLUS swapped MFMA operands: mfma(w_frag,x_frag)
//      puts output COLS on the reg axis -> float4 stores (16 vs 64 instrs).

typedef int i32x4 __attribute__((ext_vector_type(4)));

#define BM 128
#define BN 128
#define KB 64  // K-bytes per tile = quant layout block size

// -------- quantize: one block per row; OUTPUT IS K-BLOCKED q[kb][row][64] ---
__global__ __launch_bounds__(256) void quant_rows_kernel(
    const float* __restrict__ in, signed char* __restrict__ q,
    float* __restrict__ rowmax, int K, int R) {
  const int row = blockIdx.x;
  const int t = threadIdx.x;
  const size_t base = (size_t)row * K;
  float4 v = reinterpret_cast<const float4*>(in + base)[t];
  float a = fmaxf(fmaxf(fabsf(v.x), fabsf(v.y)), fmaxf(fabsf(v.z), fabsf(v.w)));
#pragma unroll
  for (int off = 32; off > 0; off >>= 1) a = fmaxf(a, __shfl_xor(a, off, 64));
  __shared__ float smax[4];
  if ((t & 63) == 0) smax[t >> 6] = a;
  __syncthreads();
  float m = fmaxf(fmaxf(smax[0], smax[1]), fmaxf(smax[2], smax[3]));
  float s = 127.0f / m;  // fp32 divide, same as reference
  char4 qq;
  qq.x = (signed char)(int)rintf(v.x * s);
  qq.y = (signed char)(int)rintf(v.y * s);
  qq.z = (signed char)(int)rintf(v.z * s);
  qq.w = (signed char)(int)rintf(v.w * s);
  // elems k = 4t..4t+3 -> kb = t>>4, within-block byte (t&15)*4
  const int kb = t >> 4;
  signed char* dst = q + (size_t)kb * R * KB + (size_t)row * KB + (t & 15) * 4;
  *reinterpret_cast<char4*>(dst) = qq;
  if (t == 0) rowmax[row] = m;
}

// -------- int8 GEMM, 128x128 tile, 4 waves (2x2): A->reg direct, B->LDS -----
__device__ __forceinline__ void gload_lds16(const void* g, void* l) {
  __builtin_amdgcn_global_load_lds(
      (const __attribute__((address_space(1))) unsigned char*)g,
      (__attribute__((address_space(3))) unsigned char*)l, 16, 0, 0);
}

__global__ __launch_bounds__(256, 4) void w8x8_gemm_kernel(
    const signed char* __restrict__ Aq, const signed char* __restrict__ Bq,
    const float* __restrict__ Amax, const float* __restrict__ Bmax,
    const float* __restrict__ bias, float* __restrict__ out,
    int M, int N, int K, int cpx) {
  // B only: 2 buffers x 8 KB = 16 KB LDS. Blocks/CU bound by VGPRs (4).
  __shared__ __align__(16) signed char ldsB[2][BN * KB];
  const int t = threadIdx.x;
  const int lane = t & 63;
  const int wave = t >> 6;
  const int wrow = wave >> 1, wcol = wave & 1;

  // XCD-chunked swizzle: contiguous bm-run per XCD (A slice 4 MB = one L2).
  const int nbn = N / BN;
  const int bid = blockIdx.x;
  const int tile = (bid & 7) * cpx + (bid >> 3);
  const int bm = tile / nbn, bn = tile % nbn;

  const size_t kbA = (size_t)M * KB;
  const size_t kbB = (size_t)N * KB;
  const int fr = lane & 15, fq = lane >> 4;

  // A direct: lane (fr,fq) reads rows wrow*64+m*16+fr, k-chunk fq. Per load
  // instruction the wave covers 1024 CONTIGUOUS bytes (K-blocked layout).
  const signed char* pa =
      Aq + (size_t)bm * BM * KB + ((wrow * 64 + fr) << 6) + (fq << 4);

  // B staging (R9-proven): 8 KB = 2 stmts x 256 thr x 16 B; dest linear,
  // source pre-swizzled chunk ^= (row>>1)&3.
  const signed char* Bbase = Bq + (size_t)bn * BN * KB;
  const int rS = t >> 2;
  const int gs0 = (rS << 6) | ((((t & 3) ^ ((rS >> 1) & 3))) << 4);
  const int dst0 = t * 16;

  // B fragment reads (swizzled): row rb, chunk fq -> rb*64 + ((fq^((rb>>1)&3))<<4)
  const int pcs = (fq ^ ((fr >> 1) & 3)) << 4;
  int boff[4];
#pragma unroll
  for (int n = 0; n < 4; ++n) boff[n] = (wcol * 64 + n * 16 + fr) * KB + pcs;

  i32x4 acc[4][4];
#pragma unroll
  for (int m = 0; m < 4; ++m)
#pragma unroll
    for (int n = 0; n < 4; ++n) acc[m][n] = (i32x4){0, 0, 0, 0};

#define STAGE_B(bf, kt)                                          \
  do {                                                           \
    const signed char* gb = Bbase + (size_t)(kt) * kbB + gs0;    \
    gload_lds16(gb, &ldsB[bf][dst0]);                            \
    gload_lds16(gb + 4096, &ldsB[bf][dst0 + 4096]);              \
  } while (0)

#define LOADA(A_, kt)                                            \
  do {                                                           \
    const signed char* ga = pa + (size_t)(kt) * kbA;             \
    A_[0] = *reinterpret_cast<const i32x4*>(ga);                 \
    A_[1] = *reinterpret_cast<const i32x4*>(ga + 1024);          \
    A_[2] = *reinterpret_cast<const i32x4*>(ga + 2048);          \
    A_[3] = *reinterpret_cast<const i32x4*>(ga + 3072);          \
  } while (0)

  // One K-step: B-frags from LDS, MFMA with SWAPPED operands:
  // mfma(w_frag, x_frag) -> D reg-axis = output COLUMN (float4 epilogue).
#define KSTEP(A_, kt, PF, AN_)                                         \
  do {                                                                 \
    const bool pf = (PF);                                              \
    if (pf) {                                                          \
      STAGE_B((kt + 1) & 1, kt + 1);                                   \
      LOADA(AN_, kt + 1);                                              \
      asm volatile("s_waitcnt vmcnt(6)" ::: "memory");                 \
    } else {                                                           \
      asm volatile("s_waitcnt vmcnt(0)" ::: "memory");                 \
    }                                                                  \
    __builtin_amdgcn_s_barrier();                                      \
    const signed char* lB = ldsB[(kt) & 1];                            \
    __builtin_amdgcn_s_setprio(1);                                     \
    _Pragma("unroll") for (int n = 0; n < 4; ++n) {                    \
      i32x4 bn = *reinterpret_cast<const i32x4*>(lB + boff[n]);        \
      _Pragma("unroll") for (int m = 0; m < 4; ++m) acc[m][n] =        \
          __builtin_amdgcn_mfma_i32_16x16x64_i8(bn, A_[m], acc[m][n],  \
                                                0, 0, 0);              \
    }                                                                  \
    __builtin_amdgcn_s_setprio(0);                                     \
    if (pf) __builtin_amdgcn_s_barrier();                              \
  } while (0)

  const int NT = K / KB;  // 16 (even)
  i32x4 aE[4], aO[4];
  STAGE_B(0, 0);
  LOADA(aE, 0);
  for (int kt = 0; kt < NT; kt += 2) {
    KSTEP(aE, kt, true, aO);                    // uses aE, prefetches aO
    KSTEP(aO, kt + 1, (kt + 2 < NT), aE);       // uses aO, prefetches aE
  }
#undef KSTEP
#undef LOADA
#undef STAGE_B

  // Epilogue (swapped layout): out row = row0 + m*16 + fr,
  // out cols = col0 + n*16 + fq*4 + r  -> float4 store per (m,n).
  const int row0 = bm * BM + wrow * 64;
  const int col0 = bn * BN + wcol * 64;
  const float C = 1.0f / 16129.0f;
  float4 wv[4], bv[4];
  int cb[4];
#pragma unroll
  for (int n = 0; n < 4; ++n) {
    cb[n] = col0 + n * 16 + fq * 4;
    wv[n] = *reinterpret_cast<const float4*>(&Bmax[cb[n]]);
    bv[n] = *reinterpret_cast<const float4*>(&bias[cb[n]]);
  }
#pragma unroll
  for (int m = 0; m < 4; ++m) {
    int row = row0 + m * 16 + fr;
    float xm = Amax[row];
    float* orow = out + (size_t)row * N;
#pragma unroll
    for (int n = 0; n < 4; ++n) {
      float4 o;
#pragma unroll
      for (int r = 0; r < 4; ++r) {
        float v = (float)acc[m][n][r] * C;
        float h = __half2float(__float2half_rn(v));  // fp16 rounding step
        float wm = (r == 0) ? wv[n].x : (r == 1) ? wv[n].y : (r == 2) ? wv[n].z : wv[n].w;
        float bb = (r == 0) ? bv[n].x : (r == 1) ? bv[n].y : (r == 2) ? bv[n].z : bv[n].w;
        ((float*)&o)[r] = h * (xm * wm) + bb;
      }
      *reinterpret_cast<float4*>(&orow[cb[n]]) = o;
    }
  }
}

extern "C" void kernel_launch(void* const* d_in, const int* in_sizes, int n_in,
                              void* d_out, int out_size, void* d_ws, size_t ws_size,
                              hipStream_t stream) {
  const float* x = (const float*)d_in[0];     // [B,S,K] fp32
  const float* w = (const float*)d_in[1];     // [N,K] fp32
  const float* bias = (const float*)d_in[2];  // [N] fp32
  float* out = (float*)d_out;                 // [B,S,N] fp32

  const int N = in_sizes[2];
  const int K = in_sizes[1] / N;   // 1024
  const int M = in_sizes[0] / K;   // 32768

  // workspace layout: x_q | w_q | x_max | w_max  (~34.7 MB total)
  signed char* xq = (signed char*)d_ws;
  signed char* wq = xq + (size_t)M * K;
  float* xmax = (float*)(wq + (size_t)N * K);
  float* wmax = xmax + M;

  quant_rows_kernel<<<M, 256, 0, stream>>>(x, xq, xmax, K, M);
  quant_rows_kernel<<<N, 256, 0, stream>>>(w, wq, wmax, K, N);

  const int nwg = (M / BM) * (N / BN);  // 2048, divisible by 8
  const int cpx = nwg / 8;
  w8x8_gemm_kernel<<<nwg, 256, 0, stream>>>(xq, wq, xmax, wmax, bias, out,
                                            M, N, K, cpx);
}

// Round 13
// 94.037 us; speedup vs baseline: 1.1817x; 1.0662x over previous
//
#include <hip/hip_runtime.h>
#include <hip/hip_fp16.h>

// W8X8Linear: per-row int8 quant (x and w), int8 GEMM via MFMA, dequant+bias.
// M=B*S=32768, N=1024, K=1024 (derived from in_sizes at launch).
//
// Exact-replication notes:
//  - jnp.round == round-half-even == rintf (v_rndne_f32)
//  - scale 127.0f/max (fp32 div) then fp32 mul, like the reference
//  - int32 accumulation == reference's fp32 einsum (|acc| < 2^24, exact)
//  - dequant: * (1/16129), fp16 RN cast, fp32 * (xmax*wmax) + bias
//
// R6: K-BLOCKED quant layout q[kb][row][64] (contiguous staging): 95us.
// R9: thin regs -> 4 waves/SIMD, BK=64, both operands LDS-staged: 89us (best).
// R10: full no-LDS: 111us (compiler sank unpinned prefetch; VGPR=72 proof).
// R11: A-direct + swapped epilogue: 100us — CONFOUNDED: swapped epilogue is
//      64x16B scattered segments/store (vs R9's 4x64B), and aE/aO pushed the
//      live set (~140) over the (256,4) 128-reg cap -> partial spill.
// R12: isolate A-direct on the R9 base. B: LDS 2-buf (16 KB only). A: direct
//      global->reg, NAMED dbuf sets, pinned by asm vmcnt+barrier. In the
//      K-blocked layout an A wave-load = 16 CONSECUTIVE 64B lines (the
//      float4-copy pattern, not R3's scatter). R9 epilogue kept verbatim.
//      Register budget fits (256,4): acc64 + aEaO32 + b(live=1)4 + addr ~20.

typedef int i32x4 __attribute__((ext_vector_type(4)));

#define BM 128
#define BN 128
#define KB 64  // K-bytes per tile = quant layout block size

// -------- quantize: one block per row; OUTPUT IS K-BLOCKED q[kb][row][64] ---
__global__ __launch_bounds__(256) void quant_rows_kernel(
    const float* __restrict__ in, signed char* __restrict__ q,
    float* __restrict__ rowmax, int K, int R) {
  const int row = blockIdx.x;
  const int t = threadIdx.x;
  const size_t base = (size_t)row * K;
  float4 v = reinterpret_cast<const float4*>(in + base)[t];
  float a = fmaxf(fmaxf(fabsf(v.x), fabsf(v.y)), fmaxf(fabsf(v.z), fabsf(v.w)));
#pragma unroll
  for (int off = 32; off > 0; off >>= 1) a = fmaxf(a, __shfl_xor(a, off, 64));
  __shared__ float smax[4];
  if ((t & 63) == 0) smax[t >> 6] = a;
  __syncthreads();
  float m = fmaxf(fmaxf(smax[0], smax[1]), fmaxf(smax[2], smax[3]));
  float s = 127.0f / m;  // fp32 divide, same as reference
  char4 qq;
  qq.x = (signed char)(int)rintf(v.x * s);
  qq.y = (signed char)(int)rintf(v.y * s);
  qq.z = (signed char)(int)rintf(v.z * s);
  qq.w = (signed char)(int)rintf(v.w * s);
  // elems k = 4t..4t+3 -> kb = t>>4, within-block byte (t&15)*4
  const int kb = t >> 4;
  signed char* dst = q + (size_t)kb * R * KB + (size_t)row * KB + (t & 15) * 4;
  *reinterpret_cast<char4*>(dst) = qq;
  if (t == 0) rowmax[row] = m;
}

// ---- int8 GEMM, 128x128 tile, 4 waves (2x2): A global->reg, B via LDS ------
__device__ __forceinline__ void gload_lds16(const void* g, void* l) {
  __builtin_amdgcn_global_load_lds(
      (const __attribute__((address_space(1))) unsigned char*)g,
      (__attribute__((address_space(3))) unsigned char*)l, 16, 0, 0);
}

__global__ __launch_bounds__(256, 4) void w8x8_gemm_kernel(
    const signed char* __restrict__ Aq, const signed char* __restrict__ Bq,
    const float* __restrict__ Amax, const float* __restrict__ Bmax,
    const float* __restrict__ bias, float* __restrict__ out,
    int M, int N, int K, int cpx) {
  // B only: 2 buffers x 8 KB = 16 KB LDS; blocks/CU = 4 (VGPR-bound).
  __shared__ __align__(16) signed char ldsB[2][BN * KB];
  const int t = threadIdx.x;
  const int lane = t & 63;
  const int wave = t >> 6;
  const int wrow = wave >> 1, wcol = wave & 1;

  // XCD-chunked swizzle: contiguous bm-run per XCD (A slice 4 MB = one L2).
  const int nbn = N / BN;
  const int bid = blockIdx.x;
  const int tile = (bid & 7) * cpx + (bid >> 3);
  const int bm = tile / nbn, bn = tile % nbn;

  const size_t kbA = (size_t)M * KB;
  const size_t kbB = (size_t)N * KB;
  const int fr = lane & 15, fq = lane >> 4;

  // A direct: lane (fr,fq) reads rows wrow*64+m*16+fr, k-chunk fq. Per load
  // instruction the wave covers 1024 CONTIGUOUS bytes (16 consecutive 64B
  // lines — float4-copy pattern).
  const signed char* pa =
      Aq + (size_t)bm * BM * KB + ((wrow * 64 + fr) << 6) + (fq << 4);

  // B staging (R9-proven): 8 KB = 2 stmts x 256 thr x 16 B; dest linear,
  // source pre-swizzled chunk ^= (row>>1)&3.
  const signed char* Bbase = Bq + (size_t)bn * BN * KB;
  const int rS = t >> 2;
  const int gs0 = (rS << 6) | ((((t & 3) ^ ((rS >> 1) & 3))) << 4);
  const int dst0 = t * 16;

  // B fragment reads (swizzled): row rb, chunk fq -> rb*64 + ((fq^((rb>>1)&3))<<4)
  const int pcs = (fq ^ ((fr >> 1) & 3)) << 4;
  int boff[4];
#pragma unroll
  for (int n = 0; n < 4; ++n) boff[n] = (wcol * 64 + n * 16 + fr) * KB + pcs;

  i32x4 acc[4][4];
#pragma unroll
  for (int m = 0; m < 4; ++m)
#pragma unroll
    for (int n = 0; n < 4; ++n) acc[m][n] = (i32x4){0, 0, 0, 0};

#define STAGE_B(bf, kt)                                          \
  do {                                                           \
    const signed char* gb = Bbase + (size_t)(kt) * kbB + gs0;    \
    gload_lds16(gb, &ldsB[bf][dst0]);                            \
    gload_lds16(gb + 4096, &ldsB[bf][dst0 + 4096]);              \
  } while (0)

#define LOADA(A_, kt)                                            \
  do {                                                           \
    const signed char* ga = pa + (size_t)(kt) * kbA;             \
    A_[0] = *reinterpret_cast<const i32x4*>(ga);                 \
    A_[1] = *reinterpret_cast<const i32x4*>(ga + 1024);          \
    A_[2] = *reinterpret_cast<const i32x4*>(ga + 2048);          \
    A_[3] = *reinterpret_cast<const i32x4*>(ga + 3072);          \
  } while (0)

  // One K-step. B-frags read ONE at a time (live-b = 1 -> reg budget).
  // Standard operand order (R9 epilogue mapping preserved).
#define KSTEP(A_, kt, PF, AN_)                                         \
  do {                                                                 \
    const bool pf = (PF);                                              \
    if (pf) {                                                          \
      STAGE_B((kt + 1) & 1, kt + 1);                                   \
      LOADA(AN_, kt + 1);                                              \
      asm volatile("s_waitcnt vmcnt(6)" ::: "memory");                 \
    } else {                                                           \
      asm volatile("s_waitcnt vmcnt(0)" ::: "memory");                 \
    }                                                                  \
    __builtin_amdgcn_s_barrier();                                      \
    const signed char* lB = ldsB[(kt) & 1];                            \
    __builtin_amdgcn_s_setprio(1);                                     \
    _Pragma("unroll") for (int n = 0; n < 4; ++n) {                    \
      i32x4 bf_ = *reinterpret_cast<const i32x4*>(lB + boff[n]);       \
      _Pragma("unroll") for (int m = 0; m < 4; ++m) acc[m][n] =        \
          __builtin_amdgcn_mfma_i32_16x16x64_i8(A_[m], bf_, acc[m][n], \
                                                0, 0, 0);              \
    }                                                                  \
    __builtin_amdgcn_s_setprio(0);                                     \
    if (pf) __builtin_amdgcn_s_barrier();                              \
  } while (0)

  const int NT = K / KB;  // 16 (even)
  i32x4 aE[4], aO[4];
  STAGE_B(0, 0);
  LOADA(aE, 0);
  for (int kt = 0; kt < NT; kt += 2) {
    KSTEP(aE, kt, true, aO);                 // uses aE(kt), prefetches aO(kt+1)
    KSTEP(aO, kt + 1, (kt + 2 < NT), aE);    // uses aO, prefetches aE(kt+2)
  }
#undef KSTEP
#undef LOADA
#undef STAGE_B

  // Epilogue: EXACT R9 form. C/D layout col = lane&15, row = (lane>>4)*4+reg.
  // Per store instr: 4 segments x 64 B (good coalescing).
  const int row0 = bm * BM + wrow * 64;
  const int col0 = bn * BN + wcol * 64;
  const float C = 1.0f / 16129.0f;
  float wmx[4], bs[4];
#pragma unroll
  for (int n = 0; n < 4; ++n) {
    int col = col0 + n * 16 + fr;
    wmx[n] = Bmax[col];
    bs[n] = bias[col];
  }
#pragma unroll
  for (int m = 0; m < 4; ++m) {
#pragma unroll
    for (int r = 0; r < 4; ++r) {
      int row = row0 + m * 16 + fq * 4 + r;
      float xm = Amax[row];
      float* orow = out + (size_t)row * N;
#pragma unroll
      for (int n = 0; n < 4; ++n) {
        float v = (float)acc[m][n][r] * C;
        float h = __half2float(__float2half_rn(v));  // fp16 rounding step
        orow[col0 + n * 16 + fr] = h * (xm * wmx[n]) + bs[n];
      }
    }
  }
}

extern "C" void kernel_launch(void* const* d_in, const int* in_sizes, int n_in,
                              void* d_out, int out_size, void* d_ws, size_t ws_size,
                              hipStream_t stream) {
  const float* x = (const float*)d_in[0];     // [B,S,K] fp32
  const float* w = (const float*)d_in[1];     // [N,K] fp32
  const float* bias = (const float*)d_in[2];  // [N] fp32
  float* out = (float*)d_out;                 // [B,S,N] fp32

  const int N = in_sizes[2];
  const int K = in_sizes[1] / N;   // 1024
  const int M = in_sizes[0] / K;   // 32768

  // workspace layout: x_q | w_q | x_max | w_max  (~34.7 MB total)
  signed char* xq = (signed char*)d_ws;
  signed char* wq = xq + (size_t)M * K;
  float* xmax = (float*)(wq + (size_t)N * K);
  float* wmax = xmax + M;

  quant_rows_kernel<<<M, 256, 0, stream>>>(x, xq, xmax, K, M);
  quant_rows_kernel<<<N, 256, 0, stream>>>(w, wq, wmax, K, N);

  const int nwg = (M / BM) * (N / BN);  // 2048, divisible by 8
  const int cpx = nwg / 8;
  w8x8_gemm_kernel<<<nwg, 256, 0, stream>>>(xq, wq, xmax, wmax, bias, out,
                                            M, N, K, cpx);
}